// Round 11
// baseline (11.900 us; speedup 1.0000x reference)
//
#include <hip/hip_runtime.h>
#include <float.h>

// Problem constants (from reference)
#define NB 5                    // N_BANDS
#define BB 256                  // B
#define LL 800                  // L
#define TT (NB * LL)            // 4000 values per batch row
#define NN (TT - NB)            // 3995 output diffs per row

constexpr int BLOCK = 1024;     // 16 waves, one block per row
constexpr int NBUK  = 2048;     // lambda ~= 2
constexpr int CAP   = 12;       // padded bucket capacity (P(overflow) ~ 5e-8/bucket)
constexpr int NV4   = TT / 4;   // 1000 float4 loads cover the row exactly
constexpr int OVFMX = 64;       // overflow list capacity (never filled in practice)

__global__ __launch_bounds__(BLOCK)
void padded_bucket_diff(const float* __restrict__ in,
                        const int* __restrict__ ntotal,
                        float* __restrict__ out)
{
    __shared__ __align__(16) float pscat[NBUK * CAP];  // 96 KB fixed-slot buckets
    __shared__ __align__(16) float srt[TT + 8];        // sorted; +8 pad for b128 tail
    __shared__ __align__(16) int   cnt[NBUK];          // histogram (atomic returns offset)
    __shared__ __align__(16) int   bstart[NBUK];       // bucket begin (scan result)
    __shared__ int   wsum[16];                         // per-wave scan totals
    __shared__ int   novf;                             // overflow count (0 in practice)
    __shared__ float ovf_v[OVFMX];
    __shared__ int   ovf_g[OVFMX];

    const int b    = blockIdx.x;
    const int tid  = threadIdx.x;
    const int lane = tid & 63;
    const int wid  = tid >> 6;
    const bool active = (tid < NV4);
    const float scale = (float)NBUK / 1000.0f;         // monotone map, vals in [0,1000)

    // ---- Prefetch global loads before init+barrier (hide HBM latency).
    float4 x4 = make_float4(0.f, 0.f, 0.f, 0.f);
    if (active) {
        int band = tid / 200;             // 200 float4 per (band,row) chunk of 800
        int l4   = tid - band * 200;
        x4 = *(reinterpret_cast<const float4*>(in + (band * BB + b) * LL) + l4);
    }
    const int nt = ntotal[b];

    // ---- Init: zero histogram, FLT_MAX-prefill padded buckets (empty slots
    //      compare greater than every real value, so rank needs no size lookup).
    *reinterpret_cast<int2*>(&cnt[tid * 2]) = make_int2(0, 0);
    const float4 fm4 = make_float4(FLT_MAX, FLT_MAX, FLT_MAX, FLT_MAX);
    #pragma unroll
    for (int k = 0; k < (NBUK * CAP) / (BLOCK * 4); ++k)      // 6 x b128 per thread
        *reinterpret_cast<float4*>(&pscat[tid * 4 + k * (BLOCK * 4)]) = fm4;
    if (tid == 0) novf = 0;
    __syncthreads();                                            // (1)

    // ---- Phase 1: classify; atomic returns slot; scatter DIRECTLY (no scan dep).
    float v[4];
    int   g[4];
    int   off[4];   // <CAP: slot index; >=CAP: CAP + overflow-list index
    if (active) {
        v[0] = x4.x; v[1] = x4.y; v[2] = x4.z; v[3] = x4.w;
        #pragma unroll
        for (int k = 0; k < 4; ++k) {
            int gg = (int)(v[k] * scale);
            gg = gg < 0 ? 0 : (gg > NBUK - 1 ? NBUK - 1 : gg);
            g[k] = gg;
            int o = atomicAdd(&cnt[gg], 1);
            if (o < CAP) {
                pscat[gg * CAP + o] = v[k];
                off[k] = o;
            } else {                       // effectively-never; exact fallback
                int oi = atomicAdd(&novf, 1);
                if (oi < OVFMX) { ovf_v[oi] = v[k]; ovf_g[oi] = gg; }
                off[k] = CAP + oi;
            }
        }
    } else {
        g[0] = g[1] = g[2] = g[3] = -1;
    }
    __syncthreads();                                            // (2)

    // ---- Phase 2: in-bucket rank (3 independent b128 window reads per element)
    //      CONCURRENT with the prefix scan — neither depends on the other.
    const int nov = novf;                  // LDS broadcast, uniform
    int rb[4];
    if (active) {
        #pragma unroll
        for (int k = 0; k < 4; ++k) {
            const float* wp = &pscat[g[k] * CAP];
            float4 a = *reinterpret_cast<const float4*>(wp);
            float4 c = *reinterpret_cast<const float4*>(wp + 4);
            float4 d = *reinterpret_cast<const float4*>(wp + 8);
            float w12[12] = {a.x, a.y, a.z, a.w, c.x, c.y, c.z, c.w, d.x, d.y, d.z, d.w};
            float x = v[k];
            int   r = 0;
            if (off[k] < CAP) {            // in-slot: tie-break by slot index
                int p = off[k];
                #pragma unroll
                for (int j = 0; j < CAP; ++j)
                    r += (w12[j] < x || (w12[j] == x && j < p)) ? 1 : 0;
                if (nov > 0)               // uniform-false in practice
                    for (int i = 0; i < nov && i < OVFMX; ++i)
                        if (ovf_g[i] == g[k]) r += (ovf_v[i] < x) ? 1 : 0;
            } else {                        // overflow element: ranks after slot ties
                int myi = off[k] - CAP;
                #pragma unroll
                for (int j = 0; j < CAP; ++j)
                    r += (w12[j] <= x) ? 1 : 0;
                for (int i = 0; i < nov && i < OVFMX; ++i)
                    if (i != myi && ovf_g[i] == g[k]) {
                        float w = ovf_v[i];
                        r += (w < x || (w == x && i < myi)) ? 1 : 0;
                    }
            }
            rb[k] = r;
        }
    }
    // prefix scan over 2048 bucket counts (2/thread), overlapped with ranks above
    int2 cc = *reinterpret_cast<int2*>(&cnt[tid * 2]);
    int  s  = cc.x + cc.y;
    int  inc = s;
    #pragma unroll
    for (int d = 1; d < 64; d <<= 1) {
        int t = __shfl_up(inc, d);
        if (lane >= d) inc += t;
    }
    if (lane == 63) wsum[wid] = inc;
    __syncthreads();                                            // (3)
    int wo = 0;
    #pragma unroll
    for (int w = 0; w < 16; ++w) wo += (w < wid) ? wsum[w] : 0;
    int run = (inc - s) + wo;
    *reinterpret_cast<int2*>(&bstart[tid * 2]) = make_int2(run, run + cc.x);
    __syncthreads();                                            // (4)

    // ---- Phase 3: final placement — one read + one write per element.
    if (active) {
        #pragma unroll
        for (int k = 0; k < 4; ++k)
            srt[bstart[g[k]] + rb[k]] = v[k];
    }
    __syncthreads();                                            // (5)

    // ---- Phase 4: adjacent diffs via two aligned b128 LDS reads per thread.
    if (tid < 999) {
        int j0 = 4 + 4 * tid;                 // 16B-aligned
        float4 p0 = *reinterpret_cast<const float4*>(&srt[j0]);
        float4 p1 = *reinterpret_cast<const float4*>(&srt[j0 + 4]);   // pad-safe
        float d0 = p0.y - p0.x;
        float d1 = p0.z - p0.y;
        float d2 = p0.w - p0.z;
        float d3 = p1.x - p0.w;
        int i0 = 4 * tid;
        float* o = out + b * NN + i0;
        o[0] = (i0     < nt) ? d0 : 0.0f;
        o[1] = (i0 + 1 < nt) ? d1 : 0.0f;
        o[2] = (i0 + 2 < nt) ? d2 : 0.0f;
        if (i0 + 3 < NN) o[3] = (i0 + 3 < nt) ? d3 : 0.0f;
    }
}

extern "C" void kernel_launch(void* const* d_in, const int* in_sizes, int n_in,
                              void* d_out, int out_size, void* d_ws, size_t ws_size,
                              hipStream_t stream) {
    const float* in  = (const float*)d_in[0];   // (5, 256, 800) fp32
    const int*   nt  = (const int*)d_in[1];     // (256,) int32
    float*       out = (float*)d_out;           // (256, 3995) fp32
    (void)in_sizes; (void)n_in; (void)out_size; (void)d_ws; (void)ws_size;
    padded_bucket_diff<<<BB, BLOCK, 0, stream>>>(in, nt, out);
}

// Round 12
// 11.442 us; speedup vs baseline: 1.0401x; 1.0401x over previous
//
#include <hip/hip_runtime.h>
#include <float.h>

// Problem constants (from reference)
#define NB 5                    // N_BANDS
#define BB 256                  // B
#define LL 800                  // L
#define TT (NB * LL)            // 4000 values per batch row
#define NN (TT - NB)            // 3995 output diffs per row

constexpr int BLOCK = 1024;     // 16 waves, one block per row
constexpr int NBUK  = 4096;     // lambda ~= 0.98
constexpr int BPT   = NBUK / BLOCK;  // 4 buckets per thread in the scan
constexpr int NV    = TT / 4;   // 1000 float4-loader threads (exactly covers row)

// Best-measured kernel of the session (R5: 11.488 us, absmax 0).
// Structure: 1 block/row, 16 waves; fused histogram+scatter-offset via
// returning LDS atomic; shuffle-based 4096-bucket scan; deterministic
// scatter; per-bucket rank-count; adjacent diff. Six structural variants
// (R6-R11) all landed within +-0.4 us of this -> latency-floor regime.
__global__ __launch_bounds__(BLOCK)
void bucket_rank_diff2(const float* __restrict__ in,
                       const int* __restrict__ ntotal,
                       float* __restrict__ out)
{
    __shared__ float scat[TT];          // bucket-grouped values
    __shared__ float srt[TT];           // fully sorted
    __shared__ int   cnt[NBUK];         // histogram (atomic, returns in-bucket offset)
    __shared__ int   bstart[NBUK + 1];  // bucket begin; bstart[NBUK] = TT sentinel
    __shared__ int   wsum[16];          // per-wave scan totals

    const int b    = blockIdx.x;
    const int tid  = threadIdx.x;
    const int lane = tid & 63;
    const int wid  = tid >> 6;

    #pragma unroll
    for (int k = 0; k < BPT; ++k) cnt[tid + k * BLOCK] = 0;
    __syncthreads();

    // ---- Phase 1: one float4 load per thread; histogram atomic RETURNS the
    //      within-bucket offset (fuses histogram and scatter-slot assignment).
    float v[4];
    int   g[4];
    int   off[4];
    const bool active = (tid < NV);     // 1000 threads x 4 elements = 4000 exactly
    if (active) {
        int band = tid / 200;           // 200 float4 per (band,row) chunk of 800 floats
        int l4   = tid - band * 200;
        const float4* p = reinterpret_cast<const float4*>(in + (band * BB + b) * LL) + l4;
        float4 x4 = *p;                 // 16B aligned: (band*256+b)*3200 bytes
        v[0] = x4.x; v[1] = x4.y; v[2] = x4.z; v[3] = x4.w;
        const float scale = (float)NBUK / 1000.0f;   // monotone map, values in [0,1000)
        #pragma unroll
        for (int k = 0; k < 4; ++k) {
            int gg = (int)(v[k] * scale);
            gg = gg < 0 ? 0 : (gg > NBUK - 1 ? NBUK - 1 : gg);
            g[k]   = gg;
            off[k] = atomicAdd(&cnt[gg], 1);   // in-bucket arrival order
        }
    } else {
        g[0] = g[1] = g[2] = g[3] = -1;
    }
    __syncthreads();

    // ---- Phase 2: exclusive prefix sum over 4096 bucket counts (1 barrier).
    int c[BPT];
    int s = 0;
    #pragma unroll
    for (int k = 0; k < BPT; ++k) { c[k] = cnt[BPT * tid + k]; s += c[k]; }
    int inc = s;
    #pragma unroll
    for (int d = 1; d < 64; d <<= 1) {
        int t = __shfl_up(inc, d);
        if (lane >= d) inc += t;
    }
    if (lane == 63) wsum[wid] = inc;
    __syncthreads();
    int wo = 0;                          // redundant per-thread wave-offset (LDS broadcast)
    #pragma unroll
    for (int w = 0; w < 16; ++w) wo += (w < wid) ? wsum[w] : 0;
    int run = (inc - s) + wo;
    #pragma unroll
    for (int k = 0; k < BPT; ++k) { bstart[BPT * tid + k] = run; run += c[k]; }
    if (tid == 0) bstart[NBUK] = TT;
    __syncthreads();

    // ---- Phase 3: deterministic scatter — NO atomics, position = bstart + off.
    int pos[4];
    if (active) {
        #pragma unroll
        for (int k = 0; k < 4; ++k) {
            pos[k] = bstart[g[k]] + off[k];
            scat[pos[k]] = v[k];
        }
    }
    __syncthreads();

    // ---- Phase 4: parallel rank-count within bucket (scatter pos = tie-break).
    if (active) {
        #pragma unroll
        for (int k = 0; k < 4; ++k) {
            int lo = bstart[g[k]];
            int hi = bstart[g[k] + 1];
            float x = v[k];
            int   p = pos[k];
            int   r = lo;
            for (int j = lo; j < hi; ++j) {
                float w = scat[j];
                if (w < x || (w == x && j < p)) ++r;
            }
            srt[r] = x;
        }
    }
    __syncthreads();

    // ---- Phase 5: adjacent diffs of sorted[4:], masked, coalesced store.
    const int nt = ntotal[b];
    #pragma unroll
    for (int k = 0; k < 4; ++k) {
        int i = tid + k * BLOCK;
        if (i < NN) {
            float d = srt[i + NB] - srt[i + NB - 1];
            out[b * NN + i] = (i < nt) ? d : 0.0f;
        }
    }
}

extern "C" void kernel_launch(void* const* d_in, const int* in_sizes, int n_in,
                              void* d_out, int out_size, void* d_ws, size_t ws_size,
                              hipStream_t stream) {
    const float* in  = (const float*)d_in[0];   // (5, 256, 800) fp32
    const int*   nt  = (const int*)d_in[1];     // (256,) int32
    float*       out = (float*)d_out;           // (256, 3995) fp32
    (void)in_sizes; (void)n_in; (void)out_size; (void)d_ws; (void)ws_size;
    bucket_rank_diff2<<<BB, BLOCK, 0, stream>>>(in, nt, out);
}